// Round 4
// baseline (52.581 us; speedup 1.0000x reference)
//
#include <hip/hip_runtime.h>

#define HH 256
#define WW 256
#define PLANE (HH * WW)          // 65536
#define CORE 32                  // output rows per strip
#define HALO 16                  // temporal halo rows (>= steps per launch)
#define SLAB 64                  // CORE + 2*HALO
#define NW 16                    // waves per block (1024 threads)
#define RPW 4                    // slab rows per wave (SLAB / NW)

// One block = one 64-row slab of one image (32-row core + 16-row halo).
// u, D, rho live in registers (4 rows x 4 cols per thread).
// Horizontal neighbors: wave-internal __shfl; vertical: double-buffered LDS
// boundary rows, ONE barrier/step.
// Trapezoid schedule: a row at distance d from the core only needs to be
// exact through step ls-d, so wave w runs my_steps = max(0, ls - d_min(w))
// steps (wave-uniform branch); stale values it leaves behind are only read
// by neighbors inside their own don't-care region.
__global__ __launch_bounds__(1024, 4)
void rd_tb16_kernel(const float* __restrict__ uin,
                    const float* __restrict__ params,
                    const int* __restrict__ t,
                    float* __restrict__ uout,
                    int base, int k)
{
    __shared__ float4 vt[2][NW][64];   // each wave's top row (dr=0)
    __shared__ float4 vb[2][NW][64];   // each wave's bottom row (dr=RPW-1)

    const int blk   = blockIdx.x;
    const int b     = blk >> 3;          // image index
    const int strip = blk & 7;
    const int r0    = strip * CORE;
    const int w     = threadIdx.x >> 6;  // wave = row-group, 0..15
    const int lane  = threadIdx.x & 63;  // lane = col-group (4 cols each)
    const int c0    = lane << 2;

    int ls = t[b] - base;
    ls = ls < 0 ? 0 : (ls > k ? k : ls);

    // wave's closest-row distance from the core: waves 0..3 top halo,
    // 12..15 bottom halo, 4..11 core (d_min = 0)
    const int d_min = (w < 4) ? (13 - 4 * w) : ((w > 11) ? (4 * w - 47) : 0);
    int my_steps = ls - d_min;
    if (my_steps < 0) my_steps = 0;

    const int growbase = r0 - HALO + RPW * w;  // global row of this thread's dr=0
    const size_t ubase = (size_t)b * PLANE;
    const size_t pbase = (size_t)b * 2 * PLANE;

    float u[RPW][4], pD[RPW][4], pR[RPW][4];

    #pragma unroll
    for (int dr = 0; dr < RPW; ++dr) {
        const int grow = growbase + dr;
        const bool inimg = (grow >= 0) && (grow < HH);
        int dist = 0;
        if (grow < r0)                 dist = r0 - grow;
        else if (grow > r0 + CORE - 1) dist = grow - (r0 + CORE - 1);
        const bool needU = inimg && (dist <= ls);
        const bool needP = inimg && (dist < ls);   // params only for rows that compute

        if (needU) {
            const float4 uu = *reinterpret_cast<const float4*>(uin + ubase + (size_t)grow * WW + c0);
            u[dr][0] = uu.x; u[dr][1] = uu.y; u[dr][2] = uu.z; u[dr][3] = uu.w;
        } else {
            u[dr][0] = u[dr][1] = u[dr][2] = u[dr][3] = 0.f;
        }
        if (needP) {
            const float4 dd = *reinterpret_cast<const float4*>(params + pbase + (size_t)grow * WW + c0);
            const float4 rr = *reinterpret_cast<const float4*>(params + pbase + PLANE + (size_t)grow * WW + c0);
            pD[dr][0] = dd.x; pD[dr][1] = dd.y; pD[dr][2] = dd.z; pD[dr][3] = dd.w;
            pR[dr][0] = rr.x; pR[dr][1] = rr.y; pR[dr][2] = rr.z; pR[dr][3] = rr.w;
        } else {
            pD[dr][0] = pD[dr][1] = pD[dr][2] = pD[dr][3] = 0.f;
            pR[dr][0] = pR[dr][1] = pR[dr][2] = pR[dr][3] = 0.f;
        }
    }

    if (ls > 0) {
        // publish initial wave-boundary rows into buffer 0 (all waves)
        vt[0][w][lane] = make_float4(u[0][0], u[0][1], u[0][2], u[0][3]);
        vb[0][w][lane] = make_float4(u[RPW-1][0], u[RPW-1][1], u[RPW-1][2], u[RPW-1][3]);

        for (int s = 0; s < ls; ++s) {
            __syncthreads();                 // buf[s&1] now visible to all waves
            if (s < my_steps) {              // wave-uniform trapezoid skip
                const int cur = s & 1;

                float upr[4] = {0.f, 0.f, 0.f, 0.f};
                float dnr[4] = {0.f, 0.f, 0.f, 0.f};
                if (w > 0)      { float4 v = vb[cur][w-1][lane]; upr[0]=v.x; upr[1]=v.y; upr[2]=v.z; upr[3]=v.w; }
                if (w < NW - 1) { float4 v = vt[cur][w+1][lane]; dnr[0]=v.x; dnr[1]=v.y; dnr[2]=v.z; dnr[3]=v.w; }

                float nu[RPW][4];
                #pragma unroll
                for (int dr = 0; dr < RPW; ++dr) {
                    float lf = __shfl_up(u[dr][3], 1);
                    float rt = __shfl_down(u[dr][0], 1);
                    if (lane == 0)  lf = 0.f;
                    if (lane == 63) rt = 0.f;

                    #pragma unroll
                    for (int c = 0; c < 4; ++c) {
                        const float upv = dr ? u[dr-1][c] : upr[c];
                        const float dnv = (dr < RPW - 1) ? u[dr+1][c] : dnr[c];
                        const float lv  = c ? u[dr][c-1] : lf;
                        const float rv  = (c < 3) ? u[dr][c+1] : rt;
                        const float uc  = u[dr][c];
                        const float s4  = (upv + dnv) + (lv + rv);
                        const float lap = fmaf(-4.0f, uc, s4);
                        const float g   = fmaf(-uc, uc, uc);          // uc*(1-uc)
                        const float a   = fmaf(pD[dr][c], lap, uc);
                        const float un  = fmaf(pR[dr][c], g, a);
                        nu[dr][c] = __builtin_amdgcn_fmed3f(un, 0.0f, 1.0f);  // clamp [0,1]
                    }
                }
                #pragma unroll
                for (int dr = 0; dr < RPW; ++dr)
                    #pragma unroll
                    for (int c = 0; c < 4; ++c)
                        u[dr][c] = nu[dr][c];

                const int nxt = cur ^ 1;
                vt[nxt][w][lane] = make_float4(u[0][0], u[0][1], u[0][2], u[0][3]);
                vb[nxt][w][lane] = make_float4(u[RPW-1][0], u[RPW-1][1], u[RPW-1][2], u[RPW-1][3]);
            }
        }
    }

    // write back the 32-row core (waves 4..11 own exactly rows r0..r0+31)
    if (w >= HALO / RPW && w < (HALO + CORE) / RPW) {
        #pragma unroll
        for (int dr = 0; dr < RPW; ++dr) {
            const int grow = growbase + dr;
            *reinterpret_cast<float4*>(uout + ubase + (size_t)grow * WW + c0) =
                make_float4(u[dr][0], u[dr][1], u[dr][2], u[dr][3]);
        }
    }
}

extern "C" void kernel_launch(void* const* d_in, const int* in_sizes, int n_in,
                              void* d_out, int out_size, void* d_ws, size_t ws_size,
                              hipStream_t stream) {
    (void)in_sizes; (void)n_in; (void)out_size; (void)ws_size;
    const float* u      = (const float*)d_in[0];
    const float* params = (const float*)d_in[1];
    const int*   t      = (const int*)d_in[2];
    float*       out    = (float*)d_out;
    float*       ws     = (float*)d_ws;

    const dim3 grid(256), block(1024);
    // steps [0,16) -> ws, steps [16,31) -> out
    rd_tb16_kernel<<<grid, block, 0, stream>>>(u,  params, t, ws,  0,  16);
    rd_tb16_kernel<<<grid, block, 0, stream>>>(ws, params, t, out, 16, 15);
}

// Round 5
// 52.504 us; speedup vs baseline: 1.0015x; 1.0015x over previous
//
#include <hip/hip_runtime.h>

#define HH 256
#define WW 256
#define PLANE (HH * WW)          // 65536
#define CORE 32                  // output rows per strip
#define HALO 31                  // temporal halo rows (>= total steps = 31)
#define NW 16                    // waves per block (1024 threads)
#define RPW 6                    // slab rows per wave (96 >= 94 = CORE + 2*HALO)

// Single launch, all 31 steps. One block = one 94-row slab of one image
// (32-row core + 31-row halo each side); u, D, rho in registers
// (6 rows x 4 cols per thread). Horizontal neighbors via wave-internal
// __shfl; vertical neighbors via double-buffered LDS boundary rows with ONE
// barrier per step. Trapezoid schedule: wave w runs
// my_steps = max(0, ls - d_min(w)) steps (wave-uniform branch); stale
// neighbor rows are only consumed inside the reader's don't-care region
// (corruption lands exactly one state beyond the last needed state).
// Rows at distance d from the core are loaded only if d <= ls (u) / d < ls
// (params); unloaded rows start 0 with D=rho=0 and stay 0 (= conv zero-pad
// for out-of-image rows; garbage never reaches the core for skipped rows).
__global__ __launch_bounds__(1024, 4)
void rd_single_kernel(const float* __restrict__ uin,
                      const float* __restrict__ params,
                      const int* __restrict__ t,
                      float* __restrict__ uout)
{
    __shared__ float4 vt[2][NW][64];   // each wave's top row (dr=0)
    __shared__ float4 vb[2][NW][64];   // each wave's bottom row (dr=RPW-1)

    const int blk   = blockIdx.x;
    const int b     = blk >> 3;          // image index
    const int strip = blk & 7;
    const int r0    = strip * CORE;
    const int w     = threadIdx.x >> 6;  // wave = row-group, 0..15
    const int lane  = threadIdx.x & 63;  // lane = col-group (4 cols each)
    const int c0    = lane << 2;

    int ls = t[b];
    if (ls > 31) ls = 31;
    if (ls < 0)  ls = 0;

    // wave's closest-row distance from the core band [r0, r0+31]
    int d_min;
    if (w <= 4)       d_min = 26 - 6 * w;   // 26,20,14,8,2
    else if (w >= 11) d_min = 6 * w - 62;   // 4,10,16,22,28
    else              d_min = 0;            // core waves 5..10
    int my_steps = ls - d_min;
    if (my_steps < 0) my_steps = 0;

    const int growbase = r0 - HALO + RPW * w;  // global row of this thread's dr=0
    const size_t ubase = (size_t)b * PLANE;
    const size_t pbase = (size_t)b * 2 * PLANE;

    float u[RPW][4], pD[RPW][4], pR[RPW][4];

    #pragma unroll
    for (int dr = 0; dr < RPW; ++dr) {
        const int grow = growbase + dr;
        const bool inimg = (grow >= 0) && (grow < HH);
        int dist = 0;
        if (grow < r0)                 dist = r0 - grow;
        else if (grow > r0 + CORE - 1) dist = grow - (r0 + CORE - 1);
        const bool needU = inimg && (dist <= ls);
        const bool needP = inimg && (dist < ls);   // params only for rows that compute

        if (needU) {
            const float4 uu = *reinterpret_cast<const float4*>(uin + ubase + (size_t)grow * WW + c0);
            u[dr][0] = uu.x; u[dr][1] = uu.y; u[dr][2] = uu.z; u[dr][3] = uu.w;
        } else {
            u[dr][0] = u[dr][1] = u[dr][2] = u[dr][3] = 0.f;
        }
        if (needP) {
            const float4 dd = *reinterpret_cast<const float4*>(params + pbase + (size_t)grow * WW + c0);
            const float4 rr = *reinterpret_cast<const float4*>(params + pbase + PLANE + (size_t)grow * WW + c0);
            pD[dr][0] = dd.x; pD[dr][1] = dd.y; pD[dr][2] = dd.z; pD[dr][3] = dd.w;
            pR[dr][0] = rr.x; pR[dr][1] = rr.y; pR[dr][2] = rr.z; pR[dr][3] = rr.w;
        } else {
            pD[dr][0] = pD[dr][1] = pD[dr][2] = pD[dr][3] = 0.f;
            pR[dr][0] = pR[dr][1] = pR[dr][2] = pR[dr][3] = 0.f;
        }
    }

    if (ls > 0) {
        // publish initial wave-boundary rows into buffer 0 (all waves)
        vt[0][w][lane] = make_float4(u[0][0], u[0][1], u[0][2], u[0][3]);
        vb[0][w][lane] = make_float4(u[RPW-1][0], u[RPW-1][1], u[RPW-1][2], u[RPW-1][3]);

        for (int s = 0; s < ls; ++s) {
            __syncthreads();                 // buf[s&1] now visible to all waves
            if (s < my_steps) {              // wave-uniform trapezoid skip
                const int cur = s & 1;

                float upr[4] = {0.f, 0.f, 0.f, 0.f};
                float dnr[4] = {0.f, 0.f, 0.f, 0.f};
                if (w > 0)      { float4 v = vb[cur][w-1][lane]; upr[0]=v.x; upr[1]=v.y; upr[2]=v.z; upr[3]=v.w; }
                if (w < NW - 1) { float4 v = vt[cur][w+1][lane]; dnr[0]=v.x; dnr[1]=v.y; dnr[2]=v.z; dnr[3]=v.w; }

                float up_old[4];             // old value of row dr-1 (rolling carry)
                #pragma unroll
                for (int dr = 0; dr < RPW; ++dr) {
                    float lf = __shfl_up(u[dr][3], 1);
                    float rt = __shfl_down(u[dr][0], 1);
                    if (lane == 0)  lf = 0.f;
                    if (lane == 63) rt = 0.f;

                    float old[4], un[4];
                    #pragma unroll
                    for (int c = 0; c < 4; ++c) old[c] = u[dr][c];

                    #pragma unroll
                    for (int c = 0; c < 4; ++c) {
                        const float upv = dr ? up_old[c] : upr[c];
                        const float dnv = (dr < RPW - 1) ? u[dr+1][c] : dnr[c];
                        const float lv  = c ? old[c-1] : lf;
                        const float rv  = (c < 3) ? old[c+1] : rt;
                        const float uc  = old[c];
                        const float s4  = (upv + dnv) + (lv + rv);
                        const float lap = fmaf(-4.0f, uc, s4);
                        const float g   = fmaf(-uc, uc, uc);          // uc*(1-uc)
                        const float a   = fmaf(pD[dr][c], lap, uc);
                        const float nv  = fmaf(pR[dr][c], g, a);
                        un[c] = __builtin_amdgcn_fmed3f(nv, 0.0f, 1.0f);
                    }
                    #pragma unroll
                    for (int c = 0; c < 4; ++c) { u[dr][c] = un[c]; up_old[c] = old[c]; }
                }

                const int nxt = cur ^ 1;
                vt[nxt][w][lane] = make_float4(u[0][0], u[0][1], u[0][2], u[0][3]);
                vb[nxt][w][lane] = make_float4(u[RPW-1][0], u[RPW-1][1], u[RPW-1][2], u[RPW-1][3]);
            }
        }
    }

    // write back the 32-row core (per-row predicate; slab rows 31..62)
    #pragma unroll
    for (int dr = 0; dr < RPW; ++dr) {
        const int grow = growbase + dr;
        if (grow >= r0 && grow < r0 + CORE) {
            *reinterpret_cast<float4*>(uout + ubase + (size_t)grow * WW + c0) =
                make_float4(u[dr][0], u[dr][1], u[dr][2], u[dr][3]);
        }
    }
}

extern "C" void kernel_launch(void* const* d_in, const int* in_sizes, int n_in,
                              void* d_out, int out_size, void* d_ws, size_t ws_size,
                              hipStream_t stream) {
    (void)in_sizes; (void)n_in; (void)out_size; (void)d_ws; (void)ws_size;
    const float* u      = (const float*)d_in[0];
    const float* params = (const float*)d_in[1];
    const int*   t      = (const int*)d_in[2];
    float*       out    = (float*)d_out;

    rd_single_kernel<<<dim3(256), dim3(1024), 0, stream>>>(u, params, t, out);
}